// Round 1
// baseline (1063.734 us; speedup 1.0000x reference)
//
#include <hip/hip_runtime.h>

#define D_FEAT 64

// One edge is handled by 16 consecutive lanes; each lane owns a float4
// (16 B) slice of the 64-float feature row. Gather from src_x is a
// contiguous 64 B read per edge; scatter is 4 fp32 atomics per lane.
__global__ void lgconv_scatter(const float* __restrict__ src_x,
                               const int* __restrict__ src_idx,
                               const int* __restrict__ dst_idx,
                               const float* __restrict__ ew,
                               float* __restrict__ out,
                               int n_edges) {
    int tid = blockIdx.x * blockDim.x + threadIdx.x;
    int edge = tid >> 4;      // 16 threads per edge
    int l    = tid & 15;      // float4 slot within the 64-float row
    if (edge >= n_edges) return;

    int s = src_idx[edge];
    int d = dst_idx[edge];
    float w = ew[edge];

    const float4 v = *reinterpret_cast<const float4*>(src_x + (size_t)s * D_FEAT + l * 4);
    float* o = out + (size_t)d * D_FEAT + l * 4;
    atomicAdd(o + 0, w * v.x);
    atomicAdd(o + 1, w * v.y);
    atomicAdd(o + 2, w * v.z);
    atomicAdd(o + 3, w * v.w);
}

extern "C" void kernel_launch(void* const* d_in, const int* in_sizes, int n_in,
                              void* d_out, int out_size, void* d_ws, size_t ws_size,
                              hipStream_t stream) {
    const float* src_x      = (const float*)d_in[0];
    // d_in[1] = dst_x: only used for its node count (output rows) — not read.
    const int*   edge_index = (const int*)d_in[2];
    const float* ew         = (const float*)d_in[3];
    float*       out        = (float*)d_out;

    const int n_edges = in_sizes[3];              // edge_weight: [E,1] -> E elements
    const int* src_idx = edge_index;              // row 0
    const int* dst_idx = edge_index + n_edges;    // row 1

    // Output accumulates -> must be zeroed every call (harness poisons 0xAA once).
    hipMemsetAsync(d_out, 0, (size_t)out_size * sizeof(float), stream);

    const int block = 256;
    const long long total_threads = (long long)n_edges * 16;
    const int grid = (int)((total_threads + block - 1) / block);
    lgconv_scatter<<<grid, block, 0, stream>>>(src_x, src_idx, dst_idx, ew, out, n_edges);
}

// Round 2
// 283.310 us; speedup vs baseline: 3.7547x; 3.7547x over previous
//
#include <hip/hip_runtime.h>

#define D_FEAT 64

// ---------------- fallback (round-1) atomic kernel ----------------
__global__ void lgconv_scatter_atomic(const float* __restrict__ src_x,
                                      const int* __restrict__ src_idx,
                                      const int* __restrict__ dst_idx,
                                      const float* __restrict__ ew,
                                      float* __restrict__ out,
                                      int n_edges) {
    int tid = blockIdx.x * blockDim.x + threadIdx.x;
    int edge = tid >> 4;
    int l    = tid & 15;
    if (edge >= n_edges) return;
    int s = src_idx[edge];
    int d = dst_idx[edge];
    float w = ew[edge];
    const float4 v = *reinterpret_cast<const float4*>(src_x + (size_t)s * D_FEAT + l * 4);
    float* o = out + (size_t)d * D_FEAT + l * 4;
    atomicAdd(o + 0, w * v.x);
    atomicAdd(o + 1, w * v.y);
    atomicAdd(o + 2, w * v.z);
    atomicAdd(o + 3, w * v.w);
}

// ---------------- two-phase: counting sort by dst, then segmented gather ----------------

__global__ void k_hist(const int* __restrict__ dst, int* __restrict__ counts, int E) {
    int e = blockIdx.x * blockDim.x + threadIdx.x;
    if (e < E) atomicAdd(&counts[dst[e]], 1);
}

// Block-local exclusive scan (256 elems/block); writes local-exclusive values
// and per-block totals.
__global__ void k_scan1(const int* __restrict__ counts, int* __restrict__ offsets,
                        int* __restrict__ blocksums, int N) {
    __shared__ int tmp[256];
    int t = threadIdx.x;
    int i = blockIdx.x * 256 + t;
    int v = (i < N) ? counts[i] : 0;
    tmp[t] = v;
    __syncthreads();
    for (int d = 1; d < 256; d <<= 1) {
        int x = (t >= d) ? tmp[t - d] : 0;
        __syncthreads();
        tmp[t] += x;
        __syncthreads();
    }
    if (i < N) offsets[i] = tmp[t] - v;  // exclusive
    if (t == 255) blocksums[blockIdx.x] = tmp[255];
}

// Single-block exclusive scan of block sums (nb <= 512).
__global__ void k_scan2(int* __restrict__ blocksums, int nb) {
    __shared__ int tmp[512];
    int t = threadIdx.x;
    int v = (t < nb) ? blocksums[t] : 0;
    tmp[t] = v;
    __syncthreads();
    for (int d = 1; d < 512; d <<= 1) {
        int x = (t >= d) ? tmp[t - d] : 0;
        __syncthreads();
        tmp[t] += x;
        __syncthreads();
    }
    if (t < nb) blocksums[t] = tmp[t] - v;
}

// Add block offsets; also initialize the scatter cursors.
__global__ void k_scan3(int* __restrict__ offsets, int* __restrict__ cursor,
                        const int* __restrict__ blocksums, int N) {
    int i = blockIdx.x * blockDim.x + threadIdx.x;
    if (i < N) {
        int o = offsets[i] + blocksums[i >> 8];  // scan1 block size = 256
        offsets[i] = o;
        cursor[i]  = o;
    }
}

// Scatter (src, w) into dst-sorted buckets.
__global__ void k_scatter(const int* __restrict__ src, const int* __restrict__ dst,
                          const float* __restrict__ ew, int* __restrict__ cursor,
                          int* __restrict__ bsrc, float* __restrict__ bw, int E) {
    int e = blockIdx.x * blockDim.x + threadIdx.x;
    if (e < E) {
        int d = dst[e];
        int pos = atomicAdd(&cursor[d], 1);
        bsrc[pos] = src[e];
        bw[pos]   = ew[e];
    }
}

// One wave (64 lanes) per destination node; lane l owns feature l.
// Each edge: one coalesced 256 B row gather (L3-resident src_x) + FMA.
// Single plain store per node — zero float atomics.
__global__ void k_gather(const float* __restrict__ src_x,
                         const int* __restrict__ offsets, const int* __restrict__ counts,
                         const int* __restrict__ bsrc, const float* __restrict__ bw,
                         float* __restrict__ out, int N) {
    int wid  = (blockIdx.x * blockDim.x + threadIdx.x) >> 6;
    int lane = threadIdx.x & 63;
    if (wid >= N) return;
    int start = offsets[wid];
    int deg   = counts[wid];
    float acc = 0.f;
    for (int i = 0; i < deg; ++i) {
        int   s = bsrc[start + i];   // wave-uniform -> broadcast
        float w = bw[start + i];     // wave-uniform -> broadcast
        acc += w * src_x[(size_t)s * D_FEAT + lane];
    }
    out[(size_t)wid * D_FEAT + lane] = acc;
}

extern "C" void kernel_launch(void* const* d_in, const int* in_sizes, int n_in,
                              void* d_out, int out_size, void* d_ws, size_t ws_size,
                              hipStream_t stream) {
    const float* src_x      = (const float*)d_in[0];
    const int*   edge_index = (const int*)d_in[2];
    const float* ew         = (const float*)d_in[3];
    float*       out        = (float*)d_out;

    const int E = in_sizes[3];            // edge_weight [E,1]
    const int N = in_sizes[1] / D_FEAT;   // dst_x [N, 64]
    const int* src = edge_index;          // row 0
    const int* dst = edge_index + E;      // row 1

    // Workspace layout (256 B aligned chunks)
    auto align256 = [](size_t x) { return (x + 255) & ~(size_t)255; };
    size_t off = 0;
    size_t counts_off    = off; off += align256((size_t)N * 4);
    size_t offsets_off   = off; off += align256((size_t)N * 4);
    size_t cursor_off    = off; off += align256((size_t)N * 4);
    size_t blocksums_off = off; off += align256(512 * 4);
    size_t bsrc_off      = off; off += align256((size_t)E * 4);
    size_t bw_off        = off; off += align256((size_t)E * 4);
    size_t need = off;

    const int nb_scan = (N + 255) / 256;  // scan1 blocks

    if (ws_size < need || nb_scan > 512) {
        // fallback: atomic scatter (round-1 path)
        hipMemsetAsync(d_out, 0, (size_t)out_size * sizeof(float), stream);
        const int block = 256;
        const long long total = (long long)E * 16;
        const int grid = (int)((total + block - 1) / block);
        lgconv_scatter_atomic<<<grid, block, 0, stream>>>(src_x, src, dst, ew, out, E);
        return;
    }

    char* w = (char*)d_ws;
    int*   counts    = (int*)(w + counts_off);
    int*   offsets   = (int*)(w + offsets_off);
    int*   cursor    = (int*)(w + cursor_off);
    int*   blocksums = (int*)(w + blocksums_off);
    int*   bsrc      = (int*)(w + bsrc_off);
    float* bw        = (float*)(w + bw_off);

    hipMemsetAsync(counts, 0, (size_t)N * 4, stream);

    const int block = 256;
    k_hist<<<(E + block - 1) / block, block, 0, stream>>>(dst, counts, E);
    k_scan1<<<nb_scan, 256, 0, stream>>>(counts, offsets, blocksums, N);
    k_scan2<<<1, 512, 0, stream>>>(blocksums, nb_scan);
    k_scan3<<<(N + block - 1) / block, block, 0, stream>>>(offsets, cursor, blocksums, N);
    k_scatter<<<(E + block - 1) / block, block, 0, stream>>>(src, dst, ew, cursor, bsrc, bw, E);

    // one wave per node, 4 waves per block
    const int gather_grid = (N + 3) / 4;
    k_gather<<<gather_grid, 256, 0, stream>>>(src_x, offsets, counts, bsrc, bw, out, N);
}

// Round 3
// 203.189 us; speedup vs baseline: 5.2352x; 1.3943x over previous
//
#include <hip/hip_runtime.h>

#define D_FEAT 64

// ---------------- fallback (round-1) atomic kernel ----------------
__global__ void lgconv_scatter_atomic(const float* __restrict__ src_x,
                                      const int* __restrict__ src_idx,
                                      const int* __restrict__ dst_idx,
                                      const float* __restrict__ ew,
                                      float* __restrict__ out,
                                      int n_edges) {
    int tid = blockIdx.x * blockDim.x + threadIdx.x;
    int edge = tid >> 4;
    int l    = tid & 15;
    if (edge >= n_edges) return;
    int s = src_idx[edge];
    int d = dst_idx[edge];
    float w = ew[edge];
    const float4 v = *reinterpret_cast<const float4*>(src_x + (size_t)s * D_FEAT + l * 4);
    float* o = out + (size_t)d * D_FEAT + l * 4;
    atomicAdd(o + 0, w * v.x);
    atomicAdd(o + 1, w * v.y);
    atomicAdd(o + 2, w * v.z);
    atomicAdd(o + 3, w * v.w);
}

// ---------------- two-phase: counting sort by dst, then segmented gather ----------------

// 4 edges per thread via int4 load.
__global__ void k_hist(const int* __restrict__ dst, int* __restrict__ counts, int E4) {
    int t = blockIdx.x * blockDim.x + threadIdx.x;
    if (t < E4) {
        int4 d = reinterpret_cast<const int4*>(dst)[t];
        atomicAdd(&counts[d.x], 1);
        atomicAdd(&counts[d.y], 1);
        atomicAdd(&counts[d.z], 1);
        atomicAdd(&counts[d.w], 1);
    }
}

__global__ void k_hist_tail(const int* __restrict__ dst, int* __restrict__ counts,
                            int start, int E) {
    int e = start + blockIdx.x * blockDim.x + threadIdx.x;
    if (e < E) atomicAdd(&counts[dst[e]], 1);
}

// Block-local exclusive scan (256 elems/block).
__global__ void k_scan1(const int* __restrict__ counts, int* __restrict__ offsets,
                        int* __restrict__ blocksums, int N) {
    __shared__ int tmp[256];
    int t = threadIdx.x;
    int i = blockIdx.x * 256 + t;
    int v = (i < N) ? counts[i] : 0;
    tmp[t] = v;
    __syncthreads();
    for (int d = 1; d < 256; d <<= 1) {
        int x = (t >= d) ? tmp[t - d] : 0;
        __syncthreads();
        tmp[t] += x;
        __syncthreads();
    }
    if (i < N) offsets[i] = tmp[t] - v;  // exclusive
    if (t == 255) blocksums[blockIdx.x] = tmp[255];
}

__global__ void k_scan2(int* __restrict__ blocksums, int nb) {
    __shared__ int tmp[512];
    int t = threadIdx.x;
    int v = (t < nb) ? blocksums[t] : 0;
    tmp[t] = v;
    __syncthreads();
    for (int d = 1; d < 512; d <<= 1) {
        int x = (t >= d) ? tmp[t - d] : 0;
        __syncthreads();
        tmp[t] += x;
        __syncthreads();
    }
    if (t < nb) blocksums[t] = tmp[t] - v;
}

__global__ void k_scan3(int* __restrict__ offsets, int* __restrict__ cursor,
                        const int* __restrict__ blocksums, int N) {
    int i = blockIdx.x * blockDim.x + threadIdx.x;
    if (i < N) {
        int o = offsets[i] + blocksums[i >> 8];
        offsets[i] = o;
        cursor[i]  = o;
    }
}

// Scatter packed (src, w_bits) into dst-sorted buckets — one 8 B store per edge.
__global__ void k_scatter(const int* __restrict__ src, const int* __restrict__ dst,
                          const float* __restrict__ ew, int* __restrict__ cursor,
                          int2* __restrict__ rec, int E) {
    int e = blockIdx.x * blockDim.x + threadIdx.x;
    if (e < E) {
        int d = dst[e];
        int pos = atomicAdd(&cursor[d], 1);
        rec[pos] = make_int2(src[e], __float_as_int(ew[e]));
    }
}

// One wave per destination node; lane l owns feature l.
// Records loaded COALESCED (lane i -> record i of a 64-chunk), then broadcast
// via shfl; row loads issued 4-deep for MLP.
__global__ void k_gather(const float* __restrict__ src_x,
                         const int* __restrict__ offsets, const int* __restrict__ counts,
                         const int2* __restrict__ rec,
                         float* __restrict__ out, int N) {
    int wid  = (blockIdx.x * blockDim.x + threadIdx.x) >> 6;
    int lane = threadIdx.x & 63;
    if (wid >= N) return;
    int start = offsets[wid];
    int deg   = counts[wid];
    float acc = 0.f;

    for (int base = 0; base < deg; base += 64) {
        int m = deg - base;
        if (m > 64) m = 64;
        int2 r = (lane < m) ? rec[start + base + lane] : make_int2(0, 0);
        int   rs = r.x;
        float rw = __int_as_float(r.y);

        int i = 0;
        for (; i + 4 <= m; i += 4) {
            int s0 = __shfl(rs, i + 0), s1 = __shfl(rs, i + 1);
            int s2 = __shfl(rs, i + 2), s3 = __shfl(rs, i + 3);
            float w0 = __shfl(rw, i + 0), w1 = __shfl(rw, i + 1);
            float w2 = __shfl(rw, i + 2), w3 = __shfl(rw, i + 3);
            float v0 = src_x[(size_t)s0 * D_FEAT + lane];
            float v1 = src_x[(size_t)s1 * D_FEAT + lane];
            float v2 = src_x[(size_t)s2 * D_FEAT + lane];
            float v3 = src_x[(size_t)s3 * D_FEAT + lane];
            acc = fmaf(w0, v0, acc);
            acc = fmaf(w1, v1, acc);
            acc = fmaf(w2, v2, acc);
            acc = fmaf(w3, v3, acc);
        }
        for (; i < m; ++i) {
            int   s = __shfl(rs, i);
            float w = __shfl(rw, i);
            acc = fmaf(w, src_x[(size_t)s * D_FEAT + lane], acc);
        }
    }
    out[(size_t)wid * D_FEAT + lane] = acc;
}

extern "C" void kernel_launch(void* const* d_in, const int* in_sizes, int n_in,
                              void* d_out, int out_size, void* d_ws, size_t ws_size,
                              hipStream_t stream) {
    const float* src_x      = (const float*)d_in[0];
    const int*   edge_index = (const int*)d_in[2];
    const float* ew         = (const float*)d_in[3];
    float*       out        = (float*)d_out;

    const int E = in_sizes[3];            // edge_weight [E,1]
    const int N = in_sizes[1] / D_FEAT;   // dst_x [N, 64]
    const int* src = edge_index;          // row 0
    const int* dst = edge_index + E;      // row 1

    auto align256 = [](size_t x) { return (x + 255) & ~(size_t)255; };
    size_t off = 0;
    size_t counts_off    = off; off += align256((size_t)N * 4);
    size_t offsets_off   = off; off += align256((size_t)N * 4);
    size_t cursor_off    = off; off += align256((size_t)N * 4);
    size_t blocksums_off = off; off += align256(512 * 4);
    size_t rec_off       = off; off += align256((size_t)E * 8);
    size_t need = off;

    const int nb_scan = (N + 255) / 256;

    if (ws_size < need || nb_scan > 512) {
        hipMemsetAsync(d_out, 0, (size_t)out_size * sizeof(float), stream);
        const int block = 256;
        const long long total = (long long)E * 16;
        const int grid = (int)((total + block - 1) / block);
        lgconv_scatter_atomic<<<grid, block, 0, stream>>>(src_x, src, dst, ew, out, E);
        return;
    }

    char* w = (char*)d_ws;
    int*   counts    = (int*)(w + counts_off);
    int*   offsets   = (int*)(w + offsets_off);
    int*   cursor    = (int*)(w + cursor_off);
    int*   blocksums = (int*)(w + blocksums_off);
    int2*  rec       = (int2*)(w + rec_off);

    hipMemsetAsync(counts, 0, (size_t)N * 4, stream);

    const int block = 256;
    const int E4 = E / 4;
    if (E4 > 0)
        k_hist<<<(E4 + block - 1) / block, block, 0, stream>>>(dst, counts, E4);
    if (E4 * 4 < E)
        k_hist_tail<<<1, block, 0, stream>>>(dst, counts, E4 * 4, E);
    k_scan1<<<nb_scan, 256, 0, stream>>>(counts, offsets, blocksums, N);
    k_scan2<<<1, 512, 0, stream>>>(blocksums, nb_scan);
    k_scan3<<<(N + block - 1) / block, block, 0, stream>>>(offsets, cursor, blocksums, N);
    k_scatter<<<(E + block - 1) / block, block, 0, stream>>>(src, dst, ew, cursor, rec, E);

    const int gather_grid = (N + 3) / 4;  // one wave per node, 4 waves/block
    k_gather<<<gather_grid, 256, 0, stream>>>(src_x, offsets, counts, rec, out, N);
}